// Round 1
// baseline (606.820 us; speedup 1.0000x reference)
//
#include <hip/hip_runtime.h>
#include <math.h>

// ---------------------------------------------------------------------------
// SwinV2 block, fused bf16-MFMA. R13 = R12 minus LDS weight staging.
//  Weight panels (bf16, padded rows WB_S=104) stay in GLOBAL memory and are
//  read per-MFMA as A-fragments (L1/L2-resident, 240 KB total shared by all
//  blocks). This halves the LDS footprint (78336 -> 37376 B) -> 4 blocks/CU
//  (16 waves/CU vs 8) and removes all panel-sequencing barriers:
//   - 2 barriers per head (cross-wave qn/kn/vt) + 1 after head loop (hb
//     overlays vt/kn region) = 7 total vs ~14.
//   - proj + whole MLP loop are barrier-free: ao/hb/pm rows are wave-local
//     (written and read by the 4 lanes sharing arow), sequenced with
//     s_waitcnt lgkmcnt(0) + sched_barrier(0).
// MFMA 16x16x32 bf16: A[m][k]: m=l15,k=lg*8+i ; B[k][n]: n=l15,k=lg*8+i
//                     C[m][n]: n=l15, m=lg*4+r   (validated rounds 2-12)
// ---------------------------------------------------------------------------

constexpr int WIN=8, CD=96, RH=128, RW=128, SHF=4;

// LDS layout in shorts
constexpr int QN_S=40, VT_S=72, PM_S=72, AO_S=104, HB_S=104, WB_S=104;
constexpr int OFF_QN=0;                 // qn [64][40]            0..2560
constexpr int OFF_KN=2560;              // kn [64][40]            ..5120
constexpr int OFF_VT=5120;              // vt [32][72]            ..7424
constexpr int OFF_PM=7424;              // pm [64][72]            ..12032
constexpr int OFF_AO=12032;             // ao [64][104]           ..18688
constexpr int OFF_HB=0;                 // hb [64][104] overlays qn/kn/vt
constexpr int PAN_SH=10240;             // padded panel: 96*104 (+256 pad) shorts
constexpr int LDS_SHORTS=18688;
constexpr int LDS_BYTES = LDS_SHORTS*2; // 37376 B -> 4 blocks/CU

typedef float f32x4 __attribute__((ext_vector_type(4)));
typedef short s16x8 __attribute__((ext_vector_type(8)));
typedef short s16x4 __attribute__((ext_vector_type(4)));

#define MFMA16(a,b,c) __builtin_amdgcn_mfma_f32_16x16x32_bf16((a),(b),(c),0,0,0)
#define WAVE_LOCAL_FENCE() do { \
    asm volatile("s_waitcnt lgkmcnt(0)" ::: "memory"); \
    __builtin_amdgcn_sched_barrier(0); } while (0)

__device__ __forceinline__ short f2bf(float f) {
    __bf16 b = (__bf16)f;
    return __builtin_bit_cast(short, b);
}
__device__ __forceinline__ s16x8 ld8(const short* p) {
    return *reinterpret_cast<const s16x8*>(p);
}
__device__ __forceinline__ s16x4 pack4(float a, float b, float c, float d) {
    s16x4 r; r[0]=f2bf(a); r[1]=f2bf(b); r[2]=f2bf(c); r[3]=f2bf(d);
    return r;
}
__device__ __forceinline__ s16x8 abf_from_f32(const float* p) {
    const f32x4* q = reinterpret_cast<const f32x4*>(p);
    f32x4 a = q[0], b = q[1];
    s16x8 r;
    r[0]=f2bf(a[0]); r[1]=f2bf(a[1]); r[2]=f2bf(a[2]); r[3]=f2bf(a[3]);
    r[4]=f2bf(b[0]); r[5]=f2bf(b[1]); r[6]=f2bf(b[2]); r[7]=f2bf(b[3]);
    return r;
}
__device__ __forceinline__ int region_id(int hh, int ww) {
    int rr = (hh < RH-WIN) ? 0 : ((hh < RH-SHF) ? 1 : 2);
    int rc = (ww < RW-WIN) ? 0 : ((ww < RW-SHF) ? 1 : 2);
    return rr*3 + rc;
}
__device__ __forceinline__ float gelu_f(float h) {
    float u = h * (1.5957691216f + 0.0713548163f * h * h);
    float e = __expf(-u);
    return h * __builtin_amdgcn_rcpf(1.f + e);
}

// ---------------------------------------------------------------------------
__global__ __launch_bounds__(256) void cpb_kernel(
    const float* __restrict__ w1, const float* __restrict__ b1,
    const float* __restrict__ w2, float* __restrict__ rpb)
{
    int g = blockIdx.x*256 + threadIdx.x;
    if (g >= 225*3) return;
    int e = g/3, h = g - e*3;
    int a = e/15, bb = e - a*15;
    float z0 = (float)(a-7) * (8.0f/7.0f);
    float z1 = (float)(bb-7) * (8.0f/7.0f);
    float s0 = (z0>0.f)?1.f:((z0<0.f)?-1.f:0.f);
    float s1 = (z1>0.f)?1.f:((z1<0.f)?-1.f:0.f);
    float t0 = s0 * log2f(fabsf(z0)+1.f) * (1.f/3.f);
    float t1 = s1 * log2f(fabsf(z1)+1.f) * (1.f/3.f);
    float acc = 0.f;
    for (int k = 0; k < 512; ++k) {
        float hv = t0*w1[2*k] + t1*w1[2*k+1] + b1[k];
        hv = fmaxf(hv, 0.f);
        acc += hv * w2[h*512 + k];
    }
    rpb[g] = 16.f / (1.f + __expf(-acc));
}

__global__ __launch_bounds__(256) void biasbuild_kernel(
    const float* __restrict__ rpb, float* __restrict__ biasT)
{
    int g = blockIdx.x*256 + threadIdx.x;     // 12288
    if (g >= 3*64*64) return;
    int h = g >> 12, rem = g & 4095, i = rem >> 6, j = rem & 63;
    int ih = i>>3, iw = i&7, jh = j>>3, jw = j&7;
    int idx = (ih-jh+7)*15 + (iw-jw+7);
    biasT[g] = rpb[idx*3 + h];
}

// prepack 12 padded panels (rows of WB_S=104 shorts, 96 valid cols)
__global__ __launch_bounds__(256) void wcvt_kernel(
    const float* __restrict__ qkvw, const float* __restrict__ projw,
    const float* __restrict__ w1,   const float* __restrict__ w2,
    short* __restrict__ wpan)
{
    int i = blockIdx.x*256 + threadIdx.x;     // 110592 exact (432 blocks)
    if (i >= 12*9216) return;
    int p = i / 9216;
    int rem = i - p*9216;
    int r = rem / 96;
    int col = rem - r*96;
    float v;
    if (p < 3)        v = qkvw[((r>>5)*96 + p*32 + (r&31))*96 + col];
    else if (p == 3)  v = projw[r*96 + col];
    else if (((p-4)&1) == 0) { int c = (p-4)>>1; v = w1[(c*96 + r)*96 + col]; }
    else              { int c = (p-4)>>1; v = w2[r*384 + c*96 + col]; }
    wpan[p*PAN_SH + r*WB_S + col] = f2bf(v);
}

// ---------------------------------------------------------------------------
__global__ __launch_bounds__(256,4) void fused_kernel(
    const float* __restrict__ x,
    const float* __restrict__ n1w, const float* __restrict__ n1b,
    const float* __restrict__ qb,  const float* __restrict__ vb,
    const float* __restrict__ lgs, const float* __restrict__ pb,
    const float* __restrict__ n2w, const float* __restrict__ n2b,
    const float* __restrict__ b1,  const float* __restrict__ b2,
    const float* __restrict__ biasT,
    const short* __restrict__ wpan,   // 12 padded panels (global, L2-resident)
    float* __restrict__ out)
{
    extern __shared__ __align__(16) short smem[];
    short* qn = smem + OFF_QN;
    short* kn = smem + OFF_KN;
    short* vt = smem + OFF_VT;
    short* pm = smem + OFF_PM;
    short* ao = smem + OFF_AO;
    short* hb = smem + OFF_HB;

    const int t = threadIdx.x;
    const int l = t & 63;
    const int wv = t >> 6;
    const int l15 = l & 15;
    const int lg  = l >> 4;

    const int wid = blockIdx.x;
    const int b = wid >> 8, wi = wid & 255, wh = wi >> 4, ww = wi & 15;
    const float* xb = x + (size_t)b * (RH*RW*CD);

    // lane's own token and its global (gather == scatter) position
    const int arow = wv*16 + l15;
    const int ahs = (wh*WIN + (arow>>3) + SHF) & (RH-1);
    const int aws = (ww*WIN + (arow&7)  + SHF) & (RW-1);
    const unsigned go = ((unsigned)(b << 14) + ahs*RW + aws) * CD;
    const float* xrow = xb + (ahs*RW + aws)*CD;
    s16x8 xa[3];
    #pragma unroll
    for (int kt = 0; kt < 3; ++kt) xa[kt] = abf_from_f32(xrow + kt*32 + lg*8);

    // shift-mask bits (swapped-S layout): i = arow, j = mt*16 + lg*4 + rr
    int mbits = 0;
    {
        int regi = region_id(wh*WIN + (arow>>3), ww*WIN + (arow&7));
        #pragma unroll
        for (int mt = 0; mt < 4; ++mt)
            #pragma unroll
            for (int rr = 0; rr < 4; ++rr) {
                int j = mt*16 + lg*4 + rr;
                int regj = region_id(wh*WIN + (j>>3), ww*WIN + (j&7));
                mbits |= (regi != regj) << (mt*4 + rr);
            }
    }

    // ================= attention heads (swapped, R11) =================
    for (int h = 0; h < 3; ++h) {
        if (h) __syncthreads();            // WAR: prev head's kn/vt readers done
        const short* wph = wpan + h*PAN_SH;

        const float ls = __expf(fminf(lgs[h], 4.60517019f));

        // ---- QKV swapped: C[m=d][n=token], A straight from global panel ----
        f32x4 qc[2], kc[2], vc[2];
        #pragma unroll
        for (int sec = 0; sec < 3; ++sec) {
            #pragma unroll
            for (int nt = 0; nt < 2; ++nt) {
                f32x4 c = {0.f,0.f,0.f,0.f};
                const short* wp = wph + (sec*32 + nt*16 + l15)*WB_S;
                #pragma unroll
                for (int kt = 0; kt < 3; ++kt)
                    c = MFMA16(ld8(wp + kt*32 + lg*8), xa[kt], c);
                if (sec==0) qc[nt]=c; else if (sec==1) kc[nt]=c; else vc[nt]=c;
            }
        }
        #pragma unroll
        for (int nt = 0; nt < 2; ++nt) {
            f32x4 qbf = *reinterpret_cast<const f32x4*>(qb + h*32 + nt*16 + lg*4);
            f32x4 vbf = *reinterpret_cast<const f32x4*>(vb + h*32 + nt*16 + lg*4);
            #pragma unroll
            for (int rr = 0; rr < 4; ++rr) { qc[nt][rr] += qbf[rr]; vc[nt][rr] += vbf[rr]; }
        }
        // ---- L2 norms over d (lane's token): in-lane + 2 shfls ----
        float sq = 0.f, sk = 0.f;
        #pragma unroll
        for (int nt = 0; nt < 2; ++nt)
            #pragma unroll
            for (int rr = 0; rr < 4; ++rr) {
                sq += qc[nt][rr]*qc[nt][rr];
                sk += kc[nt][rr]*kc[nt][rr];
            }
        sq += __shfl_xor(sq,16); sq += __shfl_xor(sq,32);
        sk += __shfl_xor(sk,16); sk += __shfl_xor(sk,32);
        float scq = ls * __builtin_amdgcn_rsqf(fmaxf(sq, 1e-24f));
        float sck =      __builtin_amdgcn_rsqf(fmaxf(sk, 1e-24f));

        // ---- stage qn/kn packed b64, vt scalar ----
        #pragma unroll
        for (int nt = 0; nt < 2; ++nt) {
            *reinterpret_cast<s16x4*>(qn + arow*QN_S + nt*16 + lg*4) =
                pack4(qc[nt][0]*scq, qc[nt][1]*scq, qc[nt][2]*scq, qc[nt][3]*scq);
            *reinterpret_cast<s16x4*>(kn + arow*QN_S + nt*16 + lg*4) =
                pack4(kc[nt][0]*sck, kc[nt][1]*sck, kc[nt][2]*sck, kc[nt][3]*sck);
            #pragma unroll
            for (int rr = 0; rr < 4; ++rr)
                vt[(nt*16 + lg*4 + rr)*VT_S + arow] = f2bf(vc[nt][rr]);
        }
        __syncthreads();                               // RAW: qn/kn/vt visible

        // ---- rel-pos bias f32x4 ----
        f32x4 bv[4];
        const float* bh = biasT + h*4096 + arow*64;
        #pragma unroll
        for (int mt = 0; mt < 4; ++mt)
            bv[mt] = *reinterpret_cast<const f32x4*>(bh + mt*16 + lg*4);

        // ---- S^T = mfma(kn, qA): C[m=j][n=i=arow] ----
        s16x8 qA = ld8(qn + arow*QN_S + lg*8);
        f32x4 st[4];
        #pragma unroll
        for (int mt = 0; mt < 4; ++mt) {
            f32x4 z = {0.f,0.f,0.f,0.f};
            st[mt] = MFMA16(ld8(kn + (mt*16 + l15)*QN_S + lg*8), qA, z);
        }
        // ---- softmax over j ----
        float mx = -1e30f;
        #pragma unroll
        for (int mt = 0; mt < 4; ++mt)
            #pragma unroll
            for (int rr = 0; rr < 4; ++rr) {
                float v = st[mt][rr] + bv[mt][rr]
                        + (((mbits>>(mt*4+rr))&1) ? -100.f : 0.f);
                st[mt][rr] = v; mx = fmaxf(mx, v);
            }
        mx = fmaxf(mx, __shfl_xor(mx,16));
        mx = fmaxf(mx, __shfl_xor(mx,32));
        float sm = 0.f;
        #pragma unroll
        for (int mt = 0; mt < 4; ++mt)
            #pragma unroll
            for (int rr = 0; rr < 4; ++rr) {
                float e = __expf(st[mt][rr] - mx);
                st[mt][rr] = e; sm += e;
            }
        sm += __shfl_xor(sm,16);
        sm += __shfl_xor(sm,32);
        float inv = __builtin_amdgcn_rcpf(sm);
        #pragma unroll
        for (int mt = 0; mt < 4; ++mt)
            *reinterpret_cast<s16x4*>(pm + arow*PM_S + mt*16 + lg*4) =
                pack4(st[mt][0]*inv, st[mt][1]*inv, st[mt][2]*inv, st[mt][3]*inv);
        WAVE_LOCAL_FENCE();                            // pm rows are wave-local

        // ---- PV^T = mfma(vt, pm): C[m=d][n=token] -> packed ao write ----
        #pragma unroll
        for (int nt2 = 0; nt2 < 2; ++nt2) {
            f32x4 o = {0.f,0.f,0.f,0.f};
            #pragma unroll
            for (int kt = 0; kt < 2; ++kt)
                o = MFMA16(ld8(vt + (nt2*16+l15)*VT_S + kt*32 + lg*8),
                           ld8(pm + arow*PM_S + kt*32 + lg*8), o);
            *reinterpret_cast<s16x4*>(ao + arow*AO_S + h*32 + nt2*16 + lg*4) =
                pack4(o[0], o[1], o[2], o[3]);
        }
    }

    // one barrier: head-2 cross-wave kn/vt readers must finish before hb
    // (which overlays qn/kn/vt) is written in the MLP. ao rows are wave-local.
    __syncthreads();

    // ================= proj^T + LN1 + residual (barrier-free) =================
    s16x8 aB[3];
    #pragma unroll
    for (int kt = 0; kt < 3; ++kt)
        aB[kt] = ld8(ao + arow*AO_S + kt*32 + lg*8);
    f32x4 pc[6];
    #pragma unroll
    for (int nt = 0; nt < 6; ++nt) {
        f32x4 c = {0.f,0.f,0.f,0.f};
        const short* wp = wpan + 3*PAN_SH + (nt*16 + l15)*WB_S;
        #pragma unroll
        for (int kt = 0; kt < 3; ++kt)
            c = MFMA16(ld8(wp + kt*32 + lg*8), aB[kt], c);
        pc[nt] = c;                                    // C[m=outc][n=token=arow]
    }

    f32x4 x1v[6];                                      // f32 residual in regs
    {
        float s = 0.f, s2 = 0.f;
        #pragma unroll
        for (int nt = 0; nt < 6; ++nt) {
            f32x4 pbf = *reinterpret_cast<const f32x4*>(pb + nt*16 + lg*4);
            #pragma unroll
            for (int rr = 0; rr < 4; ++rr) {
                float v = pc[nt][rr] + pbf[rr];
                pc[nt][rr] = v; s += v; s2 += v*v;
            }
        }
        s  += __shfl_xor(s,16);  s  += __shfl_xor(s,32);
        s2 += __shfl_xor(s2,16); s2 += __shfl_xor(s2,32);
        float mu  = s * (1.f/96.f);
        float var = s2 * (1.f/96.f) - mu*mu;
        float rstd = __builtin_amdgcn_rsqf(var + 1e-5f);
        #pragma unroll
        for (int nt = 0; nt < 6; ++nt) {
            f32x4 w1f = *reinterpret_cast<const f32x4*>(n1w + nt*16 + lg*4);
            f32x4 b1f = *reinterpret_cast<const f32x4*>(n1b + nt*16 + lg*4);
            f32x4 xv  = *reinterpret_cast<const f32x4*>(x + go + nt*16 + lg*4);
            f32x4 v;
            #pragma unroll
            for (int rr = 0; rr < 4; ++rr)
                v[rr] = xv[rr] + (pc[nt][rr] - mu)*rstd*w1f[rr] + b1f[rr];
            x1v[nt] = v;
            *reinterpret_cast<s16x4*>(ao + arow*AO_S + nt*16 + lg*4) =
                pack4(v[0], v[1], v[2], v[3]);         // x1 bf16 as GEMM source
        }
    }
    WAVE_LOCAL_FENCE();                                // x1 rows are wave-local

    // ================= MLP (swapped G1/G2, barrier-free) =================
    s16x8 x1B[3];
    #pragma unroll
    for (int kt = 0; kt < 3; ++kt)
        x1B[kt] = ld8(ao + arow*AO_S + kt*32 + lg*8);

    f32x4 oa[6];
    #pragma unroll
    for (int nt = 0; nt < 6; ++nt) oa[nt] = (f32x4){0.f,0.f,0.f,0.f};

    for (int c = 0; c < 4; ++c) {
        const short* w1p = wpan + (4+2*c)*PAN_SH;
        const short* w2p = wpan + (5+2*c)*PAN_SH;
        // G1^T: C[m=hid][n=token] -> GELU -> packed hb write
        #pragma unroll
        for (int nt = 0; nt < 6; ++nt) {
            f32x4 a = {0.f,0.f,0.f,0.f};
            const short* wp = w1p + (nt*16 + l15)*WB_S;
            #pragma unroll
            for (int kt = 0; kt < 3; ++kt)
                a = MFMA16(ld8(wp + kt*32 + lg*8), x1B[kt], a);
            f32x4 b1f = *reinterpret_cast<const f32x4*>(b1 + c*96 + nt*16 + lg*4);
            *reinterpret_cast<s16x4*>(hb + arow*HB_S + nt*16 + lg*4) =
                pack4(gelu_f(a[0]+b1f[0]), gelu_f(a[1]+b1f[1]),
                      gelu_f(a[2]+b1f[2]), gelu_f(a[3]+b1f[3]));
        }
        WAVE_LOCAL_FENCE();                            // hb rows are wave-local
        // G2^T accumulate: C[m=outc][n=token]
        s16x8 hB[3];
        #pragma unroll
        for (int kt = 0; kt < 3; ++kt)
            hB[kt] = ld8(hb + arow*HB_S + kt*32 + lg*8);
        #pragma unroll
        for (int nt = 0; nt < 6; ++nt) {
            const short* wp = w2p + (nt*16 + l15)*WB_S;
            #pragma unroll
            for (int kt = 0; kt < 3; ++kt)
                oa[nt] = MFMA16(ld8(wp + kt*32 + lg*8), hB[kt], oa[nt]);
        }
        WAVE_LOCAL_FENCE();                            // hB consumed before next G1 write
    }

    // ---- +b2, LN2, +x1 residual (f32 regs), f32x4 stores ----
    {
        float s = 0.f, s2 = 0.f;
        #pragma unroll
        for (int nt = 0; nt < 6; ++nt) {
            f32x4 b2f = *reinterpret_cast<const f32x4*>(b2 + nt*16 + lg*4);
            #pragma unroll
            for (int rr = 0; rr < 4; ++rr) {
                float v = oa[nt][rr] + b2f[rr];
                oa[nt][rr] = v; s += v; s2 += v*v;
            }
        }
        s  += __shfl_xor(s,16);  s  += __shfl_xor(s,32);
        s2 += __shfl_xor(s2,16); s2 += __shfl_xor(s2,32);
        float mu  = s * (1.f/96.f);
        float var = s2 * (1.f/96.f) - mu*mu;
        float rstd = __builtin_amdgcn_rsqf(var + 1e-5f);
        #pragma unroll
        for (int nt = 0; nt < 6; ++nt) {
            f32x4 w2f = *reinterpret_cast<const f32x4*>(n2w + nt*16 + lg*4);
            f32x4 bb2 = *reinterpret_cast<const f32x4*>(n2b + nt*16 + lg*4);
            f32x4 res;
            #pragma unroll
            for (int rr = 0; rr < 4; ++rr)
                res[rr] = x1v[nt][rr] + (oa[nt][rr] - mu)*rstd*w2f[rr] + bb2[rr];
            *reinterpret_cast<f32x4*>(out + go + nt*16 + lg*4) = res;
        }
    }
}

// ---------------------------------------------------------------------------
extern "C" void kernel_launch(void* const* d_in, const int* in_sizes, int n_in,
                              void* d_out, int out_size, void* d_ws, size_t ws_size,
                              hipStream_t stream) {
    const float* x       = (const float*)d_in[0];
    const float* norm1_w = (const float*)d_in[1];
    const float* norm1_b = (const float*)d_in[2];
    const float* qkv_w   = (const float*)d_in[3];
    const float* q_bias  = (const float*)d_in[4];
    const float* v_bias  = (const float*)d_in[5];
    const float* lgs     = (const float*)d_in[6];
    const float* cpb_w1  = (const float*)d_in[7];
    const float* cpb_b1  = (const float*)d_in[8];
    const float* cpb_w2  = (const float*)d_in[9];
    const float* proj_w  = (const float*)d_in[10];
    const float* proj_b  = (const float*)d_in[11];
    const float* norm2_w = (const float*)d_in[12];
    const float* norm2_b = (const float*)d_in[13];
    const float* mlp_w1  = (const float*)d_in[14];
    const float* mlp_b1  = (const float*)d_in[15];
    const float* mlp_w2  = (const float*)d_in[16];
    const float* mlp_b2  = (const float*)d_in[17];

    char* wsb = (char*)d_ws;
    float* rpbTab = (float*)wsb;                     // 675 f32   @ 0
    float* biasT  = (float*)(wsb + 4096);            // 12288 f32 @ 4096
    short* wpan   = (short*)(wsb + 53248);           // 12 padded panels (240 KB)

    float* out = (float*)d_out;

    hipFuncSetAttribute(reinterpret_cast<const void*>(fused_kernel),
                        hipFuncAttributeMaxDynamicSharedMemorySize, LDS_BYTES);

    cpb_kernel<<<3, 256, 0, stream>>>(cpb_w1, cpb_b1, cpb_w2, rpbTab);
    biasbuild_kernel<<<48, 256, 0, stream>>>(rpbTab, biasT);
    wcvt_kernel<<<432, 256, 0, stream>>>(qkv_w, proj_w, mlp_w1, mlp_w2, wpan);
    fused_kernel<<<8192, 256, LDS_BYTES, stream>>>(x, norm1_w, norm1_b,
                                                   q_bias, v_bias, lgs, proj_b,
                                                   norm2_w, norm2_b, mlp_b1, mlp_b2,
                                                   biasT, wpan, out);
}

// Round 2
// 459.904 us; speedup vs baseline: 1.3194x; 1.3194x over previous
//
#include <hip/hip_runtime.h>
#include <math.h>

// ---------------------------------------------------------------------------
// SwinV2 block, fused bf16-MFMA. R14 = R12 structure (LDS-staged dbuf weight
// panels, deep prefetch, ~14 barriers) + all wave-local LDS transposes
// (qn / pm / ao / hb) replaced by in-register shuffle transposes (xposeT):
// the lg-transpose exchanges data only among the 4 lanes sharing l15, so
// 8 ds_bpermute + 4 cndmask replace an LDS write+read round trip, with
// bit-identical numerics (bf16 pack happens before the exchange either way).
// Only truly cross-wave buffers stay in LDS: kn [64][40], vt [32][72].
// LDS: 78336 -> 50688 B  => 3 blocks/CU (12 waves/CU, 3/SIMD) vs 2.
// MFMA 16x16x32 bf16: A[m][k]: m=l15,k=lg*8+i ; B[k][n]: n=l15,k=lg*8+i
//                     C[m][n]: n=l15, m=lg*4+r   (validated rounds 2-13)
// xposeT: in: p0,p1 = lane's packed s16x4 of v[base+{0,16}+lg*4+rr]
//         out: s16x8 f[i] = v[base+lg*8+i]   (verified: 32kt+8lg+i algebra)
// ---------------------------------------------------------------------------

constexpr int WIN=8, CD=96, RH=128, RW=128, SHF=4;

// LDS layout in shorts
constexpr int KN_S=40, VT_S=72, WB_S=104;
constexpr int OFF_KN=0;                 // kn [64][40]            0..2560
constexpr int OFF_VT=2560;              // vt [32][72]            ..4864
constexpr int PAN_SH=10240;             // padded panel: 96*104 (+256 pad) shorts
constexpr int OFF_WB0=4864;             // panel buf0             ..15104
constexpr int OFF_WB1=15104;            // panel buf1             ..25344
constexpr int LDS_SHORTS=25344;
constexpr int LDS_BYTES = LDS_SHORTS*2; // 50688 B -> 3 blocks/CU

typedef float f32x4 __attribute__((ext_vector_type(4)));
typedef short s16x8 __attribute__((ext_vector_type(8)));
typedef short s16x4 __attribute__((ext_vector_type(4)));
typedef int   i32x2 __attribute__((ext_vector_type(2)));
typedef int   i32x4 __attribute__((ext_vector_type(4)));

#define MFMA16(a,b,c) __builtin_amdgcn_mfma_f32_16x16x32_bf16((a),(b),(c),0,0,0)

__device__ __forceinline__ short f2bf(float f) {
    __bf16 b = (__bf16)f;
    return __builtin_bit_cast(short, b);
}
__device__ __forceinline__ s16x8 ld8(const short* p) {
    return *reinterpret_cast<const s16x8*>(p);
}
__device__ __forceinline__ s16x4 pack4(float a, float b, float c, float d) {
    s16x4 r; r[0]=f2bf(a); r[1]=f2bf(b); r[2]=f2bf(c); r[3]=f2bf(d);
    return r;
}
__device__ __forceinline__ s16x8 abf_from_f32(const float* p) {
    const f32x4* q = reinterpret_cast<const f32x4*>(p);
    f32x4 a = q[0], b = q[1];
    s16x8 r;
    r[0]=f2bf(a[0]); r[1]=f2bf(a[1]); r[2]=f2bf(a[2]); r[3]=f2bf(a[3]);
    r[4]=f2bf(b[0]); r[5]=f2bf(b[1]); r[6]=f2bf(b[2]); r[7]=f2bf(b[3]);
    return r;
}
// wave-local lg-transpose: p0,p1 hold v[base+{0,16}+lg*4+rr] (packed bf16);
// returns B-fragment f[i] = v[base+lg*8+i] for this lane's lg.
__device__ __forceinline__ s16x8 xposeT(s16x4 p0, s16x4 p1, int l) {
    const int l15 = l & 15, lg = l >> 4;
    const int L1 = l15 + (((2*lg  )&3)<<4);
    const int L2 = l15 + (((2*lg+1)&3)<<4);
    i32x2 q0 = __builtin_bit_cast(i32x2, p0);
    i32x2 q1 = __builtin_bit_cast(i32x2, p1);
    const bool lo = (lg & 2) == 0;          // pack select = lg>>1
    int a0 = __shfl(q0[0], L1), b0 = __shfl(q1[0], L1);
    int a1 = __shfl(q0[1], L1), b1 = __shfl(q1[1], L1);
    int a2 = __shfl(q0[0], L2), b2 = __shfl(q1[0], L2);
    int a3 = __shfl(q0[1], L2), b3 = __shfl(q1[1], L2);
    i32x4 w;
    w[0] = lo ? a0 : b0;
    w[1] = lo ? a1 : b1;
    w[2] = lo ? a2 : b2;
    w[3] = lo ? a3 : b3;
    return __builtin_bit_cast(s16x8, w);
}
__device__ __forceinline__ int region_id(int hh, int ww) {
    int rr = (hh < RH-WIN) ? 0 : ((hh < RH-SHF) ? 1 : 2);
    int rc = (ww < RW-WIN) ? 0 : ((ww < RW-SHF) ? 1 : 2);
    return rr*3 + rc;
}
__device__ __forceinline__ float gelu_f(float h) {
    float u = h * (1.5957691216f + 0.0713548163f * h * h);
    float e = __expf(-u);
    return h * __builtin_amdgcn_rcpf(1.f + e);
}

// async stage of one padded 20480-B panel into LDS (linear dest, 20 chunks)
__device__ __forceinline__ void stage_panel(const short* __restrict__ pan,
                                            short* dst, int wv, int l) {
    const char* g = (const char*)pan + l*16;
    char* d = (char*)dst;
    #pragma unroll
    for (int k = 0; k < 5; ++k) {
        int i = wv + k*4;                 // exactly 20 chunks of 1024 B / 4 waves
        __builtin_amdgcn_global_load_lds(
            (const __attribute__((address_space(1))) unsigned int*)(g + i*1024),
            (__attribute__((address_space(3))) unsigned int*)(d + i*1024),
            16, 0, 0);
    }
}

// ---------------------------------------------------------------------------
__global__ __launch_bounds__(256) void cpb_kernel(
    const float* __restrict__ w1, const float* __restrict__ b1,
    const float* __restrict__ w2, float* __restrict__ rpb)
{
    int g = blockIdx.x*256 + threadIdx.x;
    if (g >= 225*3) return;
    int e = g/3, h = g - e*3;
    int a = e/15, bb = e - a*15;
    float z0 = (float)(a-7) * (8.0f/7.0f);
    float z1 = (float)(bb-7) * (8.0f/7.0f);
    float s0 = (z0>0.f)?1.f:((z0<0.f)?-1.f:0.f);
    float s1 = (z1>0.f)?1.f:((z1<0.f)?-1.f:0.f);
    float t0 = s0 * log2f(fabsf(z0)+1.f) * (1.f/3.f);
    float t1 = s1 * log2f(fabsf(z1)+1.f) * (1.f/3.f);
    float acc = 0.f;
    for (int k = 0; k < 512; ++k) {
        float hv = t0*w1[2*k] + t1*w1[2*k+1] + b1[k];
        hv = fmaxf(hv, 0.f);
        acc += hv * w2[h*512 + k];
    }
    rpb[g] = 16.f / (1.f + __expf(-acc));
}

__global__ __launch_bounds__(256) void biasbuild_kernel(
    const float* __restrict__ rpb, float* __restrict__ biasT)
{
    int g = blockIdx.x*256 + threadIdx.x;     // 12288
    if (g >= 3*64*64) return;
    int h = g >> 12, rem = g & 4095, i = rem >> 6, j = rem & 63;
    int ih = i>>3, iw = i&7, jh = j>>3, jw = j&7;
    int idx = (ih-jh+7)*15 + (iw-jw+7);
    biasT[g] = rpb[idx*3 + h];
}

// prepack 12 padded panels (rows of WB_S=104 shorts, 96 valid cols)
__global__ __launch_bounds__(256) void wcvt_kernel(
    const float* __restrict__ qkvw, const float* __restrict__ projw,
    const float* __restrict__ w1,   const float* __restrict__ w2,
    short* __restrict__ wpan)
{
    int i = blockIdx.x*256 + threadIdx.x;     // 110592 exact (432 blocks)
    if (i >= 12*9216) return;
    int p = i / 9216;
    int rem = i - p*9216;
    int r = rem / 96;
    int col = rem - r*96;
    float v;
    if (p < 3)        v = qkvw[((r>>5)*96 + p*32 + (r&31))*96 + col];
    else if (p == 3)  v = projw[r*96 + col];
    else if (((p-4)&1) == 0) { int c = (p-4)>>1; v = w1[(c*96 + r)*96 + col]; }
    else              { int c = (p-4)>>1; v = w2[r*384 + c*96 + col]; }
    wpan[p*PAN_SH + r*WB_S + col] = f2bf(v);
}

// ---------------------------------------------------------------------------
__global__ __launch_bounds__(256,4) void fused_kernel(
    const float* __restrict__ x,
    const float* __restrict__ n1w, const float* __restrict__ n1b,
    const float* __restrict__ qb,  const float* __restrict__ vb,
    const float* __restrict__ lgs, const float* __restrict__ pb,
    const float* __restrict__ n2w, const float* __restrict__ n2b,
    const float* __restrict__ b1,  const float* __restrict__ b2,
    const float* __restrict__ biasT,
    const short* __restrict__ wpan,   // 12 padded panels
    float* __restrict__ out)
{
    extern __shared__ __align__(16) short smem[];
    short* kn  = smem + OFF_KN;
    short* vt  = smem + OFF_VT;
    short* wb0 = smem + OFF_WB0;
    short* wb1 = smem + OFF_WB1;

    const int t = threadIdx.x;
    const int l = t & 63;
    const int wv = t >> 6;
    const int l15 = l & 15;
    const int lg  = l >> 4;

    const int wid = blockIdx.x;
    const int b = wid >> 8, wi = wid & 255, wh = wi >> 4, ww = wi & 15;
    const float* xb = x + (size_t)b * (RH*RW*CD);

    // lane's own token and its global (gather == scatter) position
    const int arow = wv*16 + l15;
    const int ahs = (wh*WIN + (arow>>3) + SHF) & (RH-1);
    const int aws = (ww*WIN + (arow&7)  + SHF) & (RW-1);
    const unsigned go = ((unsigned)(b << 14) + ahs*RW + aws) * CD;
    const float* xrow = xb + (ahs*RW + aws)*CD;
    s16x8 xa[3];
    #pragma unroll
    for (int kt = 0; kt < 3; ++kt) xa[kt] = abf_from_f32(xrow + kt*32 + lg*8);

    // shift-mask bits (swapped-S layout): i = arow, j = mt*16 + lg*4 + rr
    int mbits = 0;
    {
        int regi = region_id(wh*WIN + (arow>>3), ww*WIN + (arow&7));
        #pragma unroll
        for (int mt = 0; mt < 4; ++mt)
            #pragma unroll
            for (int rr = 0; rr < 4; ++rr) {
                int j = mt*16 + lg*4 + rr;
                int regj = region_id(wh*WIN + (j>>3), ww*WIN + (j&7));
                mbits |= (regi != regj) << (mt*4 + rr);
            }
    }

    stage_panel(wpan, wb0, wv, l);                     // P0 -> buf0 (async)

    s16x4 aop[6];                                      // attn out, packed bf16

    // ================= attention heads (swapped) =================
    #pragma unroll
    for (int h = 0; h < 3; ++h) {
        __syncthreads();                   // panel h landed; prev consumers done
        stage_panel(wpan + (h+1)*PAN_SH, (h&1) ? wb0 : wb1, wv, l);
        const short* wbuf = (h&1) ? wb1 : wb0;

        const float ls = __expf(fminf(lgs[h], 4.60517019f));

        // ---- QKV swapped: C[m=d][n=token] ----
        f32x4 qc[2], kc[2], vc[2];
        #pragma unroll
        for (int sec = 0; sec < 3; ++sec) {
            #pragma unroll
            for (int nt = 0; nt < 2; ++nt) {
                f32x4 c = {0.f,0.f,0.f,0.f};
                const short* wp = wbuf + (sec*32 + nt*16 + l15)*WB_S;
                #pragma unroll
                for (int kt = 0; kt < 3; ++kt)
                    c = MFMA16(ld8(wp + kt*32 + lg*8), xa[kt], c);
                if (sec==0) qc[nt]=c; else if (sec==1) kc[nt]=c; else vc[nt]=c;
            }
        }
        #pragma unroll
        for (int nt = 0; nt < 2; ++nt) {
            f32x4 qbf = *reinterpret_cast<const f32x4*>(qb + h*32 + nt*16 + lg*4);
            f32x4 vbf = *reinterpret_cast<const f32x4*>(vb + h*32 + nt*16 + lg*4);
            #pragma unroll
            for (int rr = 0; rr < 4; ++rr) { qc[nt][rr] += qbf[rr]; vc[nt][rr] += vbf[rr]; }
        }
        // ---- L2 norms over d (lane's token): in-lane + 2 shfls ----
        float sq = 0.f, sk = 0.f;
        #pragma unroll
        for (int nt = 0; nt < 2; ++nt)
            #pragma unroll
            for (int rr = 0; rr < 4; ++rr) {
                sq += qc[nt][rr]*qc[nt][rr];
                sk += kc[nt][rr]*kc[nt][rr];
            }
        sq += __shfl_xor(sq,16); sq += __shfl_xor(sq,32);
        sk += __shfl_xor(sk,16); sk += __shfl_xor(sk,32);
        float scq = ls * __builtin_amdgcn_rsqf(fmaxf(sq, 1e-24f));
        float sck =      __builtin_amdgcn_rsqf(fmaxf(sk, 1e-24f));

        // ---- q stays in regs (packed); kn/vt staged to LDS (cross-wave) ----
        s16x4 qp0 = pack4(qc[0][0]*scq, qc[0][1]*scq, qc[0][2]*scq, qc[0][3]*scq);
        s16x4 qp1 = pack4(qc[1][0]*scq, qc[1][1]*scq, qc[1][2]*scq, qc[1][3]*scq);
        #pragma unroll
        for (int nt = 0; nt < 2; ++nt) {
            *reinterpret_cast<s16x4*>(kn + arow*KN_S + nt*16 + lg*4) =
                pack4(kc[nt][0]*sck, kc[nt][1]*sck, kc[nt][2]*sck, kc[nt][3]*sck);
            #pragma unroll
            for (int rr = 0; rr < 4; ++rr)
                vt[(nt*16 + lg*4 + rr)*VT_S + arow] = f2bf(vc[nt][rr]);
        }
        __syncthreads();                               // RAW: kn/vt visible

        // ---- rel-pos bias f32x4 ----
        f32x4 bv[4];
        const float* bh = biasT + h*4096 + arow*64;
        #pragma unroll
        for (int mt = 0; mt < 4; ++mt)
            bv[mt] = *reinterpret_cast<const f32x4*>(bh + mt*16 + lg*4);

        // ---- S^T = mfma(kn, qA): C[m=j][n=i=arow] ----
        s16x8 qA = xposeT(qp0, qp1, l);
        f32x4 st[4];
        #pragma unroll
        for (int mt = 0; mt < 4; ++mt) {
            f32x4 z = {0.f,0.f,0.f,0.f};
            st[mt] = MFMA16(ld8(kn + (mt*16 + l15)*KN_S + lg*8), qA, z);
        }
        // ---- softmax over j ----
        float mx = -1e30f;
        #pragma unroll
        for (int mt = 0; mt < 4; ++mt)
            #pragma unroll
            for (int rr = 0; rr < 4; ++rr) {
                float v = st[mt][rr] + bv[mt][rr]
                        + (((mbits>>(mt*4+rr))&1) ? -100.f : 0.f);
                st[mt][rr] = v; mx = fmaxf(mx, v);
            }
        mx = fmaxf(mx, __shfl_xor(mx,16));
        mx = fmaxf(mx, __shfl_xor(mx,32));
        float sm = 0.f;
        #pragma unroll
        for (int mt = 0; mt < 4; ++mt)
            #pragma unroll
            for (int rr = 0; rr < 4; ++rr) {
                float e = __expf(st[mt][rr] - mx);
                st[mt][rr] = e; sm += e;
            }
        sm += __shfl_xor(sm,16);
        sm += __shfl_xor(sm,32);
        float inv = __builtin_amdgcn_rcpf(sm);
        s16x4 pw[4];
        #pragma unroll
        for (int mt = 0; mt < 4; ++mt)
            pw[mt] = pack4(st[mt][0]*inv, st[mt][1]*inv, st[mt][2]*inv, st[mt][3]*inv);

        // ---- PV^T = mfma(vt, P-frag): C[m=d][n=token] -> packed regs ----
        s16x8 pB0 = xposeT(pw[0], pw[1], l);
        s16x8 pB1 = xposeT(pw[2], pw[3], l);
        #pragma unroll
        for (int nt2 = 0; nt2 < 2; ++nt2) {
            f32x4 o = {0.f,0.f,0.f,0.f};
            o = MFMA16(ld8(vt + (nt2*16+l15)*VT_S + 0  + lg*8), pB0, o);
            o = MFMA16(ld8(vt + (nt2*16+l15)*VT_S + 32 + lg*8), pB1, o);
            aop[h*2 + nt2] = pack4(o[0], o[1], o[2], o[3]);
        }
    }

    // ================= proj^T + LN1 + residual (in-register) =================
    // wb0 readers (head-2 QKV) finished before head-2 RAW sync; P3 (wb1) was
    // drained by that same sync. No extra barrier needed.
    stage_panel(wpan + 4*PAN_SH, wb0, wv, l);          // P4 (w1 c0) async

    s16x8 aB[3];
    #pragma unroll
    for (int kt = 0; kt < 3; ++kt)
        aB[kt] = xposeT(aop[2*kt], aop[2*kt+1], l);
    f32x4 pc[6];
    #pragma unroll
    for (int nt = 0; nt < 6; ++nt) {
        f32x4 c = {0.f,0.f,0.f,0.f};
        const short* wp = wb1 + (nt*16 + l15)*WB_S;
        #pragma unroll
        for (int kt = 0; kt < 3; ++kt)
            c = MFMA16(ld8(wp + kt*32 + lg*8), aB[kt], c);
        pc[nt] = c;                                    // C[m=outc][n=token=arow]
    }

    f32x4 x1v[6];                                      // f32 residual in regs
    s16x4 x1p[6];                                      // packed bf16 x1
    {
        float s = 0.f, s2 = 0.f;
        #pragma unroll
        for (int nt = 0; nt < 6; ++nt) {
            f32x4 pbf = *reinterpret_cast<const f32x4*>(pb + nt*16 + lg*4);
            #pragma unroll
            for (int rr = 0; rr < 4; ++rr) {
                float v = pc[nt][rr] + pbf[rr];
                pc[nt][rr] = v; s += v; s2 += v*v;
            }
        }
        s  += __shfl_xor(s,16);  s  += __shfl_xor(s,32);
        s2 += __shfl_xor(s2,16); s2 += __shfl_xor(s2,32);
        float mu  = s * (1.f/96.f);
        float var = s2 * (1.f/96.f) - mu*mu;
        float rstd = __builtin_amdgcn_rsqf(var + 1e-5f);
        #pragma unroll
        for (int nt = 0; nt < 6; ++nt) {
            f32x4 w1f = *reinterpret_cast<const f32x4*>(n1w + nt*16 + lg*4);
            f32x4 b1f = *reinterpret_cast<const f32x4*>(n1b + nt*16 + lg*4);
            f32x4 xv  = *reinterpret_cast<const f32x4*>(x + go + nt*16 + lg*4);
            f32x4 v;
            #pragma unroll
            for (int rr = 0; rr < 4; ++rr)
                v[rr] = xv[rr] + (pc[nt][rr] - mu)*rstd*w1f[rr] + b1f[rr];
            x1v[nt] = v;
            x1p[nt] = pack4(v[0], v[1], v[2], v[3]);
        }
    }

    // ================= MLP (swapped G1/G2, in-register h) =================
    s16x8 x1B[3];
    #pragma unroll
    for (int kt = 0; kt < 3; ++kt)
        x1B[kt] = xposeT(x1p[2*kt], x1p[2*kt+1], l);

    f32x4 oa[6];
    #pragma unroll
    for (int nt = 0; nt < 6; ++nt) oa[nt] = (f32x4){0.f,0.f,0.f,0.f};

    for (int c = 0; c < 4; ++c) {
        __syncthreads();                               // w1 chunk c landed in wb0
        stage_panel(wpan + (5+2*c)*PAN_SH, wb1, wv, l);
        // G1^T: C[m=hid][n=token] -> GELU -> packed regs
        s16x4 hp[6];
        #pragma unroll
        for (int nt = 0; nt < 6; ++nt) {
            f32x4 a = {0.f,0.f,0.f,0.f};
            const short* wp = wb0 + (nt*16 + l15)*WB_S;
            #pragma unroll
            for (int kt = 0; kt < 3; ++kt)
                a = MFMA16(ld8(wp + kt*32 + lg*8), x1B[kt], a);
            f32x4 b1f = *reinterpret_cast<const f32x4*>(b1 + c*96 + nt*16 + lg*4);
            hp[nt] = pack4(gelu_f(a[0]+b1f[0]), gelu_f(a[1]+b1f[1]),
                           gelu_f(a[2]+b1f[2]), gelu_f(a[3]+b1f[3]));
        }
        __syncthreads();                               // w2 chunk landed in wb1
        if (c < 3) stage_panel(wpan + (6+2*c)*PAN_SH, wb0, wv, l);
        // G2^T accumulate: C[m=outc][n=token]
        s16x8 hB[3];
        #pragma unroll
        for (int kt = 0; kt < 3; ++kt)
            hB[kt] = xposeT(hp[2*kt], hp[2*kt+1], l);
        #pragma unroll
        for (int nt = 0; nt < 6; ++nt) {
            const short* wp = wb1 + (nt*16 + l15)*WB_S;
            #pragma unroll
            for (int kt = 0; kt < 3; ++kt)
                oa[nt] = MFMA16(ld8(wp + kt*32 + lg*8), hB[kt], oa[nt]);
        }
    }

    // ---- +b2, LN2, +x1 residual (f32 regs), f32x4 stores ----
    {
        float s = 0.f, s2 = 0.f;
        #pragma unroll
        for (int nt = 0; nt < 6; ++nt) {
            f32x4 b2f = *reinterpret_cast<const f32x4*>(b2 + nt*16 + lg*4);
            #pragma unroll
            for (int rr = 0; rr < 4; ++rr) {
                float v = oa[nt][rr] + b2f[rr];
                oa[nt][rr] = v; s += v; s2 += v*v;
            }
        }
        s  += __shfl_xor(s,16);  s  += __shfl_xor(s,32);
        s2 += __shfl_xor(s2,16); s2 += __shfl_xor(s2,32);
        float mu  = s * (1.f/96.f);
        float var = s2 * (1.f/96.f) - mu*mu;
        float rstd = __builtin_amdgcn_rsqf(var + 1e-5f);
        #pragma unroll
        for (int nt = 0; nt < 6; ++nt) {
            f32x4 w2f = *reinterpret_cast<const f32x4*>(n2w + nt*16 + lg*4);
            f32x4 bb2 = *reinterpret_cast<const f32x4*>(n2b + nt*16 + lg*4);
            f32x4 res;
            #pragma unroll
            for (int rr = 0; rr < 4; ++rr)
                res[rr] = x1v[nt][rr] + (oa[nt][rr] - mu)*rstd*w2f[rr] + bb2[rr];
            *reinterpret_cast<f32x4*>(out + go + nt*16 + lg*4) = res;
        }
    }
}

// ---------------------------------------------------------------------------
extern "C" void kernel_launch(void* const* d_in, const int* in_sizes, int n_in,
                              void* d_out, int out_size, void* d_ws, size_t ws_size,
                              hipStream_t stream) {
    const float* x       = (const float*)d_in[0];
    const float* norm1_w = (const float*)d_in[1];
    const float* norm1_b = (const float*)d_in[2];
    const float* qkv_w   = (const float*)d_in[3];
    const float* q_bias  = (const float*)d_in[4];
    const float* v_bias  = (const float*)d_in[5];
    const float* lgs     = (const float*)d_in[6];
    const float* cpb_w1  = (const float*)d_in[7];
    const float* cpb_b1  = (const float*)d_in[8];
    const float* cpb_w2  = (const float*)d_in[9];
    const float* proj_w  = (const float*)d_in[10];
    const float* proj_b  = (const float*)d_in[11];
    const float* norm2_w = (const float*)d_in[12];
    const float* norm2_b = (const float*)d_in[13];
    const float* mlp_w1  = (const float*)d_in[14];
    const float* mlp_b1  = (const float*)d_in[15];
    const float* mlp_w2  = (const float*)d_in[16];
    const float* mlp_b2  = (const float*)d_in[17];

    char* wsb = (char*)d_ws;
    float* rpbTab = (float*)wsb;                     // 675 f32   @ 0
    float* biasT  = (float*)(wsb + 4096);            // 12288 f32 @ 4096
    short* wpan   = (short*)(wsb + 53248);           // 12 padded panels (240 KB)

    float* out = (float*)d_out;

    hipFuncSetAttribute(reinterpret_cast<const void*>(fused_kernel),
                        hipFuncAttributeMaxDynamicSharedMemorySize, LDS_BYTES);

    cpb_kernel<<<3, 256, 0, stream>>>(cpb_w1, cpb_b1, cpb_w2, rpbTab);
    biasbuild_kernel<<<48, 256, 0, stream>>>(rpbTab, biasT);
    wcvt_kernel<<<432, 256, 0, stream>>>(qkv_w, proj_w, mlp_w1, mlp_w2, wpan);
    fused_kernel<<<8192, 256, LDS_BYTES, stream>>>(x, norm1_w, norm1_b,
                                                   q_bias, v_bias, lgs, proj_b,
                                                   norm2_w, norm2_b, mlp_b1, mlp_b2,
                                                   biasT, wpan, out);
}

// Round 3
// 374.750 us; speedup vs baseline: 1.6193x; 1.2272x over previous
//
#include <hip/hip_runtime.h>
#include <math.h>

// ---------------------------------------------------------------------------
// SwinV2 block, fused bf16-MFMA. R15 = R14 with the launch-bounds/occupancy
// mismatch fixed: LDS (50688 B) permits exactly 3 blocks/CU, so declare
// __launch_bounds__(256,3) (reg cap ~168) instead of (256,4) (cap 128).
// R14's cap-128 squeeze spilled the long-lived register state (x1v, aop,
// x1B) to scratch: WRITE_SIZE 197->637 MB, FETCH 101->422 MB. This fixes it.
// Structure unchanged from R14:
//  - dbuf LDS weight panels + deep global_load_lds prefetch (R12 schedule)
//  - wave-local lg-transposes in registers via xposeT (8 shfl + 4 cndmask)
//  - only cross-wave buffers in LDS: kn [64][40], vt [32][72]
// MFMA 16x16x32 bf16: A[m][k]: m=l15,k=lg*8+i ; B[k][n]: n=l15,k=lg*8+i
//                     C[m][n]: n=l15, m=lg*4+r   (validated rounds 2-14)
// ---------------------------------------------------------------------------

constexpr int WIN=8, CD=96, RH=128, RW=128, SHF=4;

// LDS layout in shorts
constexpr int KN_S=40, VT_S=72, WB_S=104;
constexpr int OFF_KN=0;                 // kn [64][40]            0..2560
constexpr int OFF_VT=2560;              // vt [32][72]            ..4864
constexpr int PAN_SH=10240;             // padded panel: 96*104 (+256 pad) shorts
constexpr int OFF_WB0=4864;             // panel buf0             ..15104
constexpr int OFF_WB1=15104;            // panel buf1             ..25344
constexpr int LDS_SHORTS=25344;
constexpr int LDS_BYTES = LDS_SHORTS*2; // 50688 B -> 3 blocks/CU

typedef float f32x4 __attribute__((ext_vector_type(4)));
typedef short s16x8 __attribute__((ext_vector_type(8)));
typedef short s16x4 __attribute__((ext_vector_type(4)));
typedef int   i32x2 __attribute__((ext_vector_type(2)));
typedef int   i32x4 __attribute__((ext_vector_type(4)));

#define MFMA16(a,b,c) __builtin_amdgcn_mfma_f32_16x16x32_bf16((a),(b),(c),0,0,0)

__device__ __forceinline__ short f2bf(float f) {
    __bf16 b = (__bf16)f;
    return __builtin_bit_cast(short, b);
}
__device__ __forceinline__ s16x8 ld8(const short* p) {
    return *reinterpret_cast<const s16x8*>(p);
}
__device__ __forceinline__ s16x4 pack4(float a, float b, float c, float d) {
    s16x4 r; r[0]=f2bf(a); r[1]=f2bf(b); r[2]=f2bf(c); r[3]=f2bf(d);
    return r;
}
__device__ __forceinline__ s16x8 abf_from_f32(const float* p) {
    const f32x4* q = reinterpret_cast<const f32x4*>(p);
    f32x4 a = q[0], b = q[1];
    s16x8 r;
    r[0]=f2bf(a[0]); r[1]=f2bf(a[1]); r[2]=f2bf(a[2]); r[3]=f2bf(a[3]);
    r[4]=f2bf(b[0]); r[5]=f2bf(b[1]); r[6]=f2bf(b[2]); r[7]=f2bf(b[3]);
    return r;
}
// wave-local lg-transpose: p0,p1 hold v[base+{0,16}+lg*4+rr] (packed bf16);
// returns B-fragment f[i] = v[base+lg*8+i] for this lane's lg.
__device__ __forceinline__ s16x8 xposeT(s16x4 p0, s16x4 p1, int l) {
    const int l15 = l & 15, lg = l >> 4;
    const int L1 = l15 + (((2*lg  )&3)<<4);
    const int L2 = l15 + (((2*lg+1)&3)<<4);
    i32x2 q0 = __builtin_bit_cast(i32x2, p0);
    i32x2 q1 = __builtin_bit_cast(i32x2, p1);
    const bool lo = (lg & 2) == 0;          // pack select = lg>>1
    int a0 = __shfl(q0[0], L1), b0 = __shfl(q1[0], L1);
    int a1 = __shfl(q0[1], L1), b1 = __shfl(q1[1], L1);
    int a2 = __shfl(q0[0], L2), b2 = __shfl(q1[0], L2);
    int a3 = __shfl(q0[1], L2), b3 = __shfl(q1[1], L2);
    i32x4 w;
    w[0] = lo ? a0 : b0;
    w[1] = lo ? a1 : b1;
    w[2] = lo ? a2 : b2;
    w[3] = lo ? a3 : b3;
    return __builtin_bit_cast(s16x8, w);
}
__device__ __forceinline__ int region_id(int hh, int ww) {
    int rr = (hh < RH-WIN) ? 0 : ((hh < RH-SHF) ? 1 : 2);
    int rc = (ww < RW-WIN) ? 0 : ((ww < RW-SHF) ? 1 : 2);
    return rr*3 + rc;
}
__device__ __forceinline__ float gelu_f(float h) {
    float u = h * (1.5957691216f + 0.0713548163f * h * h);
    float e = __expf(-u);
    return h * __builtin_amdgcn_rcpf(1.f + e);
}

// async stage of one padded 20480-B panel into LDS (linear dest, 20 chunks)
__device__ __forceinline__ void stage_panel(const short* __restrict__ pan,
                                            short* dst, int wv, int l) {
    const char* g = (const char*)pan + l*16;
    char* d = (char*)dst;
    #pragma unroll
    for (int k = 0; k < 5; ++k) {
        int i = wv + k*4;                 // exactly 20 chunks of 1024 B / 4 waves
        __builtin_amdgcn_global_load_lds(
            (const __attribute__((address_space(1))) unsigned int*)(g + i*1024),
            (__attribute__((address_space(3))) unsigned int*)(d + i*1024),
            16, 0, 0);
    }
}

// ---------------------------------------------------------------------------
__global__ __launch_bounds__(256) void cpb_kernel(
    const float* __restrict__ w1, const float* __restrict__ b1,
    const float* __restrict__ w2, float* __restrict__ rpb)
{
    int g = blockIdx.x*256 + threadIdx.x;
    if (g >= 225*3) return;
    int e = g/3, h = g - e*3;
    int a = e/15, bb = e - a*15;
    float z0 = (float)(a-7) * (8.0f/7.0f);
    float z1 = (float)(bb-7) * (8.0f/7.0f);
    float s0 = (z0>0.f)?1.f:((z0<0.f)?-1.f:0.f);
    float s1 = (z1>0.f)?1.f:((z1<0.f)?-1.f:0.f);
    float t0 = s0 * log2f(fabsf(z0)+1.f) * (1.f/3.f);
    float t1 = s1 * log2f(fabsf(z1)+1.f) * (1.f/3.f);
    float acc = 0.f;
    for (int k = 0; k < 512; ++k) {
        float hv = t0*w1[2*k] + t1*w1[2*k+1] + b1[k];
        hv = fmaxf(hv, 0.f);
        acc += hv * w2[h*512 + k];
    }
    rpb[g] = 16.f / (1.f + __expf(-acc));
}

__global__ __launch_bounds__(256) void biasbuild_kernel(
    const float* __restrict__ rpb, float* __restrict__ biasT)
{
    int g = blockIdx.x*256 + threadIdx.x;     // 12288
    if (g >= 3*64*64) return;
    int h = g >> 12, rem = g & 4095, i = rem >> 6, j = rem & 63;
    int ih = i>>3, iw = i&7, jh = j>>3, jw = j&7;
    int idx = (ih-jh+7)*15 + (iw-jw+7);
    biasT[g] = rpb[idx*3 + h];
}

// prepack 12 padded panels (rows of WB_S=104 shorts, 96 valid cols)
__global__ __launch_bounds__(256) void wcvt_kernel(
    const float* __restrict__ qkvw, const float* __restrict__ projw,
    const float* __restrict__ w1,   const float* __restrict__ w2,
    short* __restrict__ wpan)
{
    int i = blockIdx.x*256 + threadIdx.x;     // 110592 exact (432 blocks)
    if (i >= 12*9216) return;
    int p = i / 9216;
    int rem = i - p*9216;
    int r = rem / 96;
    int col = rem - r*96;
    float v;
    if (p < 3)        v = qkvw[((r>>5)*96 + p*32 + (r&31))*96 + col];
    else if (p == 3)  v = projw[r*96 + col];
    else if (((p-4)&1) == 0) { int c = (p-4)>>1; v = w1[(c*96 + r)*96 + col]; }
    else              { int c = (p-4)>>1; v = w2[r*384 + c*96 + col]; }
    wpan[p*PAN_SH + r*WB_S + col] = f2bf(v);
}

// ---------------------------------------------------------------------------
__global__ __launch_bounds__(256,3) void fused_kernel(
    const float* __restrict__ x,
    const float* __restrict__ n1w, const float* __restrict__ n1b,
    const float* __restrict__ qb,  const float* __restrict__ vb,
    const float* __restrict__ lgs, const float* __restrict__ pb,
    const float* __restrict__ n2w, const float* __restrict__ n2b,
    const float* __restrict__ b1,  const float* __restrict__ b2,
    const float* __restrict__ biasT,
    const short* __restrict__ wpan,   // 12 padded panels
    float* __restrict__ out)
{
    extern __shared__ __align__(16) short smem[];
    short* kn  = smem + OFF_KN;
    short* vt  = smem + OFF_VT;
    short* wb0 = smem + OFF_WB0;
    short* wb1 = smem + OFF_WB1;

    const int t = threadIdx.x;
    const int l = t & 63;
    const int wv = t >> 6;
    const int l15 = l & 15;
    const int lg  = l >> 4;

    const int wid = blockIdx.x;
    const int b = wid >> 8, wi = wid & 255, wh = wi >> 4, ww = wi & 15;
    const float* xb = x + (size_t)b * (RH*RW*CD);

    // lane's own token and its global (gather == scatter) position
    const int arow = wv*16 + l15;
    const int ahs = (wh*WIN + (arow>>3) + SHF) & (RH-1);
    const int aws = (ww*WIN + (arow&7)  + SHF) & (RW-1);
    const unsigned go = ((unsigned)(b << 14) + ahs*RW + aws) * CD;
    const float* xrow = xb + (ahs*RW + aws)*CD;
    s16x8 xa[3];
    #pragma unroll
    for (int kt = 0; kt < 3; ++kt) xa[kt] = abf_from_f32(xrow + kt*32 + lg*8);

    // shift-mask bits (swapped-S layout): i = arow, j = mt*16 + lg*4 + rr
    int mbits = 0;
    {
        int regi = region_id(wh*WIN + (arow>>3), ww*WIN + (arow&7));
        #pragma unroll
        for (int mt = 0; mt < 4; ++mt)
            #pragma unroll
            for (int rr = 0; rr < 4; ++rr) {
                int j = mt*16 + lg*4 + rr;
                int regj = region_id(wh*WIN + (j>>3), ww*WIN + (j&7));
                mbits |= (regi != regj) << (mt*4 + rr);
            }
    }

    stage_panel(wpan, wb0, wv, l);                     // P0 -> buf0 (async)

    s16x4 aop[6];                                      // attn out, packed bf16

    // ================= attention heads (swapped) =================
    #pragma unroll
    for (int h = 0; h < 3; ++h) {
        __syncthreads();                   // panel h landed; prev consumers done
        stage_panel(wpan + (h+1)*PAN_SH, (h&1) ? wb0 : wb1, wv, l);
        const short* wbuf = (h&1) ? wb1 : wb0;

        const float ls = __expf(fminf(lgs[h], 4.60517019f));

        // ---- QKV swapped: C[m=d][n=token] ----
        f32x4 qc[2], kc[2], vc[2];
        #pragma unroll
        for (int sec = 0; sec < 3; ++sec) {
            #pragma unroll
            for (int nt = 0; nt < 2; ++nt) {
                f32x4 c = {0.f,0.f,0.f,0.f};
                const short* wp = wbuf + (sec*32 + nt*16 + l15)*WB_S;
                #pragma unroll
                for (int kt = 0; kt < 3; ++kt)
                    c = MFMA16(ld8(wp + kt*32 + lg*8), xa[kt], c);
                if (sec==0) qc[nt]=c; else if (sec==1) kc[nt]=c; else vc[nt]=c;
            }
        }
        #pragma unroll
        for (int nt = 0; nt < 2; ++nt) {
            f32x4 qbf = *reinterpret_cast<const f32x4*>(qb + h*32 + nt*16 + lg*4);
            f32x4 vbf = *reinterpret_cast<const f32x4*>(vb + h*32 + nt*16 + lg*4);
            #pragma unroll
            for (int rr = 0; rr < 4; ++rr) { qc[nt][rr] += qbf[rr]; vc[nt][rr] += vbf[rr]; }
        }
        // ---- L2 norms over d (lane's token): in-lane + 2 shfls ----
        float sq = 0.f, sk = 0.f;
        #pragma unroll
        for (int nt = 0; nt < 2; ++nt)
            #pragma unroll
            for (int rr = 0; rr < 4; ++rr) {
                sq += qc[nt][rr]*qc[nt][rr];
                sk += kc[nt][rr]*kc[nt][rr];
            }
        sq += __shfl_xor(sq,16); sq += __shfl_xor(sq,32);
        sk += __shfl_xor(sk,16); sk += __shfl_xor(sk,32);
        float scq = ls * __builtin_amdgcn_rsqf(fmaxf(sq, 1e-24f));
        float sck =      __builtin_amdgcn_rsqf(fmaxf(sk, 1e-24f));

        // ---- q stays in regs (packed); kn/vt staged to LDS (cross-wave) ----
        s16x4 qp0 = pack4(qc[0][0]*scq, qc[0][1]*scq, qc[0][2]*scq, qc[0][3]*scq);
        s16x4 qp1 = pack4(qc[1][0]*scq, qc[1][1]*scq, qc[1][2]*scq, qc[1][3]*scq);
        #pragma unroll
        for (int nt = 0; nt < 2; ++nt) {
            *reinterpret_cast<s16x4*>(kn + arow*KN_S + nt*16 + lg*4) =
                pack4(kc[nt][0]*sck, kc[nt][1]*sck, kc[nt][2]*sck, kc[nt][3]*sck);
            #pragma unroll
            for (int rr = 0; rr < 4; ++rr)
                vt[(nt*16 + lg*4 + rr)*VT_S + arow] = f2bf(vc[nt][rr]);
        }
        __syncthreads();                               // RAW: kn/vt visible

        // ---- rel-pos bias f32x4 ----
        f32x4 bv[4];
        const float* bh = biasT + h*4096 + arow*64;
        #pragma unroll
        for (int mt = 0; mt < 4; ++mt)
            bv[mt] = *reinterpret_cast<const f32x4*>(bh + mt*16 + lg*4);

        // ---- S^T = mfma(kn, qA): C[m=j][n=i=arow] ----
        s16x8 qA = xposeT(qp0, qp1, l);
        f32x4 st[4];
        #pragma unroll
        for (int mt = 0; mt < 4; ++mt) {
            f32x4 z = {0.f,0.f,0.f,0.f};
            st[mt] = MFMA16(ld8(kn + (mt*16 + l15)*KN_S + lg*8), qA, z);
        }
        // ---- softmax over j ----
        float mx = -1e30f;
        #pragma unroll
        for (int mt = 0; mt < 4; ++mt)
            #pragma unroll
            for (int rr = 0; rr < 4; ++rr) {
                float v = st[mt][rr] + bv[mt][rr]
                        + (((mbits>>(mt*4+rr))&1) ? -100.f : 0.f);
                st[mt][rr] = v; mx = fmaxf(mx, v);
            }
        mx = fmaxf(mx, __shfl_xor(mx,16));
        mx = fmaxf(mx, __shfl_xor(mx,32));
        float sm = 0.f;
        #pragma unroll
        for (int mt = 0; mt < 4; ++mt)
            #pragma unroll
            for (int rr = 0; rr < 4; ++rr) {
                float e = __expf(st[mt][rr] - mx);
                st[mt][rr] = e; sm += e;
            }
        sm += __shfl_xor(sm,16);
        sm += __shfl_xor(sm,32);
        float inv = __builtin_amdgcn_rcpf(sm);
        s16x4 pw[4];
        #pragma unroll
        for (int mt = 0; mt < 4; ++mt)
            pw[mt] = pack4(st[mt][0]*inv, st[mt][1]*inv, st[mt][2]*inv, st[mt][3]*inv);

        // ---- PV^T = mfma(vt, P-frag): C[m=d][n=token] -> packed regs ----
        s16x8 pB0 = xposeT(pw[0], pw[1], l);
        s16x8 pB1 = xposeT(pw[2], pw[3], l);
        #pragma unroll
        for (int nt2 = 0; nt2 < 2; ++nt2) {
            f32x4 o = {0.f,0.f,0.f,0.f};
            o = MFMA16(ld8(vt + (nt2*16+l15)*VT_S + 0  + lg*8), pB0, o);
            o = MFMA16(ld8(vt + (nt2*16+l15)*VT_S + 32 + lg*8), pB1, o);
            aop[h*2 + nt2] = pack4(o[0], o[1], o[2], o[3]);
        }
    }

    // ================= proj^T + LN1 + residual (in-register) =================
    // wb0 readers (head-2 QKV) finished before head-2 RAW sync; P3 (wb1) was
    // drained by that same sync. No extra barrier needed.
    stage_panel(wpan + 4*PAN_SH, wb0, wv, l);          // P4 (w1 c0) async

    s16x8 aB[3];
    #pragma unroll
    for (int kt = 0; kt < 3; ++kt)
        aB[kt] = xposeT(aop[2*kt], aop[2*kt+1], l);
    f32x4 pc[6];
    #pragma unroll
    for (int nt = 0; nt < 6; ++nt) {
        f32x4 c = {0.f,0.f,0.f,0.f};
        const short* wp = wb1 + (nt*16 + l15)*WB_S;
        #pragma unroll
        for (int kt = 0; kt < 3; ++kt)
            c = MFMA16(ld8(wp + kt*32 + lg*8), aB[kt], c);
        pc[nt] = c;                                    // C[m=outc][n=token=arow]
    }

    f32x4 x1v[6];                                      // f32 residual in regs
    s16x4 x1p[6];                                      // packed bf16 x1
    {
        float s = 0.f, s2 = 0.f;
        #pragma unroll
        for (int nt = 0; nt < 6; ++nt) {
            f32x4 pbf = *reinterpret_cast<const f32x4*>(pb + nt*16 + lg*4);
            #pragma unroll
            for (int rr = 0; rr < 4; ++rr) {
                float v = pc[nt][rr] + pbf[rr];
                pc[nt][rr] = v; s += v; s2 += v*v;
            }
        }
        s  += __shfl_xor(s,16);  s  += __shfl_xor(s,32);
        s2 += __shfl_xor(s2,16); s2 += __shfl_xor(s2,32);
        float mu  = s * (1.f/96.f);
        float var = s2 * (1.f/96.f) - mu*mu;
        float rstd = __builtin_amdgcn_rsqf(var + 1e-5f);
        #pragma unroll
        for (int nt = 0; nt < 6; ++nt) {
            f32x4 w1f = *reinterpret_cast<const f32x4*>(n1w + nt*16 + lg*4);
            f32x4 b1f = *reinterpret_cast<const f32x4*>(n1b + nt*16 + lg*4);
            f32x4 xv  = *reinterpret_cast<const f32x4*>(x + go + nt*16 + lg*4);
            f32x4 v;
            #pragma unroll
            for (int rr = 0; rr < 4; ++rr)
                v[rr] = xv[rr] + (pc[nt][rr] - mu)*rstd*w1f[rr] + b1f[rr];
            x1v[nt] = v;
            x1p[nt] = pack4(v[0], v[1], v[2], v[3]);
        }
    }

    // ================= MLP (swapped G1/G2, in-register h) =================
    s16x8 x1B[3];
    #pragma unroll
    for (int kt = 0; kt < 3; ++kt)
        x1B[kt] = xposeT(x1p[2*kt], x1p[2*kt+1], l);

    f32x4 oa[6];
    #pragma unroll
    for (int nt = 0; nt < 6; ++nt) oa[nt] = (f32x4){0.f,0.f,0.f,0.f};

    for (int c = 0; c < 4; ++c) {
        __syncthreads();                               // w1 chunk c landed in wb0
        stage_panel(wpan + (5+2*c)*PAN_SH, wb1, wv, l);
        // G1^T: C[m=hid][n=token] -> GELU -> packed regs
        s16x4 hp[6];
        #pragma unroll
        for (int nt = 0; nt < 6; ++nt) {
            f32x4 a = {0.f,0.f,0.f,0.f};
            const short* wp = wb0 + (nt*16 + l15)*WB_S;
            #pragma unroll
            for (int kt = 0; kt < 3; ++kt)
                a = MFMA16(ld8(wp + kt*32 + lg*8), x1B[kt], a);
            f32x4 b1f = *reinterpret_cast<const f32x4*>(b1 + c*96 + nt*16 + lg*4);
            hp[nt] = pack4(gelu_f(a[0]+b1f[0]), gelu_f(a[1]+b1f[1]),
                           gelu_f(a[2]+b1f[2]), gelu_f(a[3]+b1f[3]));
        }
        __syncthreads();                               // w2 chunk landed in wb1
        if (c < 3) stage_panel(wpan + (6+2*c)*PAN_SH, wb0, wv, l);
        // G2^T accumulate: C[m=outc][n=token]
        s16x8 hB[3];
        #pragma unroll
        for (int kt = 0; kt < 3; ++kt)
            hB[kt] = xposeT(hp[2*kt], hp[2*kt+1], l);
        #pragma unroll
        for (int nt = 0; nt < 6; ++nt) {
            const short* wp = wb1 + (nt*16 + l15)*WB_S;
            #pragma unroll
            for (int kt = 0; kt < 3; ++kt)
                oa[nt] = MFMA16(ld8(wp + kt*32 + lg*8), hB[kt], oa[nt]);
        }
    }

    // ---- +b2, LN2, +x1 residual (f32 regs), f32x4 stores ----
    {
        float s = 0.f, s2 = 0.f;
        #pragma unroll
        for (int nt = 0; nt < 6; ++nt) {
            f32x4 b2f = *reinterpret_cast<const f32x4*>(b2 + nt*16 + lg*4);
            #pragma unroll
            for (int rr = 0; rr < 4; ++rr) {
                float v = oa[nt][rr] + b2f[rr];
                oa[nt][rr] = v; s += v; s2 += v*v;
            }
        }
        s  += __shfl_xor(s,16);  s  += __shfl_xor(s,32);
        s2 += __shfl_xor(s2,16); s2 += __shfl_xor(s2,32);
        float mu  = s * (1.f/96.f);
        float var = s2 * (1.f/96.f) - mu*mu;
        float rstd = __builtin_amdgcn_rsqf(var + 1e-5f);
        #pragma unroll
        for (int nt = 0; nt < 6; ++nt) {
            f32x4 w2f = *reinterpret_cast<const f32x4*>(n2w + nt*16 + lg*4);
            f32x4 bb2 = *reinterpret_cast<const f32x4*>(n2b + nt*16 + lg*4);
            f32x4 res;
            #pragma unroll
            for (int rr = 0; rr < 4; ++rr)
                res[rr] = x1v[nt][rr] + (oa[nt][rr] - mu)*rstd*w2f[rr] + bb2[rr];
            *reinterpret_cast<f32x4*>(out + go + nt*16 + lg*4) = res;
        }
    }
}

// ---------------------------------------------------------------------------
extern "C" void kernel_launch(void* const* d_in, const int* in_sizes, int n_in,
                              void* d_out, int out_size, void* d_ws, size_t ws_size,
                              hipStream_t stream) {
    const float* x       = (const float*)d_in[0];
    const float* norm1_w = (const float*)d_in[1];
    const float* norm1_b = (const float*)d_in[2];
    const float* qkv_w   = (const float*)d_in[3];
    const float* q_bias  = (const float*)d_in[4];
    const float* v_bias  = (const float*)d_in[5];
    const float* lgs     = (const float*)d_in[6];
    const float* cpb_w1  = (const float*)d_in[7];
    const float* cpb_b1  = (const float*)d_in[8];
    const float* cpb_w2  = (const float*)d_in[9];
    const float* proj_w  = (const float*)d_in[10];
    const float* proj_b  = (const float*)d_in[11];
    const float* norm2_w = (const float*)d_in[12];
    const float* norm2_b = (const float*)d_in[13];
    const float* mlp_w1  = (const float*)d_in[14];
    const float* mlp_b1  = (const float*)d_in[15];
    const float* mlp_w2  = (const float*)d_in[16];
    const float* mlp_b2  = (const float*)d_in[17];

    char* wsb = (char*)d_ws;
    float* rpbTab = (float*)wsb;                     // 675 f32   @ 0
    float* biasT  = (float*)(wsb + 4096);            // 12288 f32 @ 4096
    short* wpan   = (short*)(wsb + 53248);           // 12 padded panels (240 KB)

    float* out = (float*)d_out;

    hipFuncSetAttribute(reinterpret_cast<const void*>(fused_kernel),
                        hipFuncAttributeMaxDynamicSharedMemorySize, LDS_BYTES);

    cpb_kernel<<<3, 256, 0, stream>>>(cpb_w1, cpb_b1, cpb_w2, rpbTab);
    biasbuild_kernel<<<48, 256, 0, stream>>>(rpbTab, biasT);
    wcvt_kernel<<<432, 256, 0, stream>>>(qkv_w, proj_w, mlp_w1, mlp_w2, wpan);
    fused_kernel<<<8192, 256, LDS_BYTES, stream>>>(x, norm1_w, norm1_b,
                                                   q_bias, v_bias, lgs, proj_b,
                                                   norm2_w, norm2_b, mlp_b1, mlp_b2,
                                                   biasT, wpan, out);
}